// Round 1
// baseline (546.528 us; speedup 1.0000x reference)
//
#include <hip/hip_runtime.h>
#include <math.h>

#define NN   10000          // nodes
#define NE   160000         // raw edges
#define NET  (NE + NN)      // edges + self loops = 170000
#define FIN  70
#define HIDC 256
#define NH   4
#define D1   1024           // NH*HIDC
#define SLOPE 0.2f

// ---------------- CSR build ----------------
__global__ void k_hist(const int* __restrict__ ei, int* __restrict__ counts) {
    int e = blockIdx.x * 256 + threadIdx.x;
    if (e >= NET) return;
    int dst = (e < NE) ? ei[NE + e] : (e - NE);
    atomicAdd(&counts[dst], 1);
}

__global__ __launch_bounds__(1024) void k_scan(const int* __restrict__ counts,
                                               int* __restrict__ indptr,
                                               int* __restrict__ cursor) {
    __shared__ int ls[1024];
    int t = threadIdx.x;
    int c[10];
    int base = t * 10;
    int lsum = 0;
#pragma unroll
    for (int i = 0; i < 10; i++) {
        int j = base + i;
        c[i] = (j < NN) ? counts[j] : 0;
        lsum += c[i];
    }
    ls[t] = lsum;
    __syncthreads();
    for (int off = 1; off < 1024; off <<= 1) {
        int v = (t >= off) ? ls[t - off] : 0;
        __syncthreads();
        ls[t] += v;
        __syncthreads();
    }
    int excl = ls[t] - lsum;
#pragma unroll
    for (int i = 0; i < 10; i++) {
        int j = base + i;
        if (j < NN) { indptr[j] = excl; cursor[j] = excl; excl += c[i]; }
    }
    if (t == 1023) indptr[NN] = ls[1023];
}

__global__ void k_scatter(const int* __restrict__ ei, int* __restrict__ cursor,
                          int* __restrict__ ssrc) {
    int e = blockIdx.x * 256 + threadIdx.x;
    if (e >= NET) return;
    int src, dst;
    if (e < NE) { src = ei[e]; dst = ei[NE + e]; }
    else        { src = e - NE; dst = src; }
    int pos = atomicAdd(&cursor[dst], 1);
    ssrc[pos] = src;
}

// ---------------- GEMM1: [NN x FIN] @ [FIN x D1] ----------------
// block = 256 threads, 8 nodes per block; thread t handles cols {j*256+t}
__global__ __launch_bounds__(256) void k_gemm1(const float* __restrict__ x,
                                               const float* __restrict__ W,
                                               float* __restrict__ h1) {
    __shared__ float xs[8][FIN];
    int t = threadIdx.x;
    int n0 = blockIdx.x * 8;
    for (int idx = t; idx < 8 * FIN; idx += 256) {
        int r = idx / FIN, k = idx % FIN;
        xs[r][k] = x[(size_t)(n0 + r) * FIN + k];
    }
    __syncthreads();
    float acc[8][4] = {};
    for (int k = 0; k < FIN; k++) {
        float w0 = W[(size_t)k * D1 + t];
        float w1 = W[(size_t)k * D1 + 256 + t];
        float w2 = W[(size_t)k * D1 + 512 + t];
        float w3 = W[(size_t)k * D1 + 768 + t];
#pragma unroll
        for (int r = 0; r < 8; r++) {
            float xv = xs[r][k];
            acc[r][0] += xv * w0; acc[r][1] += xv * w1;
            acc[r][2] += xv * w2; acc[r][3] += xv * w3;
        }
    }
#pragma unroll
    for (int r = 0; r < 8; r++)
#pragma unroll
        for (int j = 0; j < 4; j++)
            h1[(size_t)(n0 + r) * D1 + j * 256 + t] = acc[r][j];
}

// ---------------- per-node attention coefficients ----------------
template <int H>
__global__ __launch_bounds__(256) void k_att(const float* __restrict__ hbuf,
                                             const float* __restrict__ asrc,
                                             const float* __restrict__ adst,
                                             float* __restrict__ asn,
                                             float* __restrict__ adn) {
    int n = blockIdx.x, t = threadIdx.x;
    __shared__ float rs[256], rd[256];
#pragma unroll
    for (int h = 0; h < H; h++) {
        float v = hbuf[(size_t)n * (H * 256) + h * 256 + t];
        rs[t] = v * asrc[h * 256 + t];
        rd[t] = v * adst[h * 256 + t];
        __syncthreads();
        for (int off = 128; off > 0; off >>= 1) {
            if (t < off) { rs[t] += rs[t + off]; rd[t] += rd[t + off]; }
            __syncthreads();
        }
        if (t == 0) { asn[n * H + h] = rs[0]; adn[n * H + h] = rd[0]; }
        __syncthreads();
    }
}

// ---------------- per-dst-node segment softmax (1 wave/node) ----------------
template <int H>
__global__ __launch_bounds__(64) void k_edge_softmax(const int* __restrict__ indptr,
                                                     const int* __restrict__ ssrc,
                                                     const float* __restrict__ as,
                                                     const float* __restrict__ ad,
                                                     float* __restrict__ alpha) {
    int d = blockIdx.x;
    int lane = threadIdx.x;
    int beg = indptr[d], end = indptr[d + 1];
    float adv[H], m[H], sum[H];
#pragma unroll
    for (int h = 0; h < H; h++) { adv[h] = ad[d * H + h]; m[h] = -1e30f; sum[h] = 0.f; }
    for (int i = beg + lane; i < end; i += 64) {
        int s = ssrc[i];
#pragma unroll
        for (int h = 0; h < H; h++) {
            float e = as[s * H + h] + adv[h];
            e = (e > 0.f) ? e : SLOPE * e;
            m[h] = fmaxf(m[h], e);
        }
    }
#pragma unroll
    for (int h = 0; h < H; h++)
        for (int off = 32; off > 0; off >>= 1)
            m[h] = fmaxf(m[h], __shfl_xor(m[h], off));
    for (int i = beg + lane; i < end; i += 64) {
        int s = ssrc[i];
#pragma unroll
        for (int h = 0; h < H; h++) {
            float e = as[s * H + h] + adv[h];
            e = (e > 0.f) ? e : SLOPE * e;
            float ex = expf(e - m[h]);
            alpha[(size_t)i * H + h] = ex;
            sum[h] += ex;
        }
    }
#pragma unroll
    for (int h = 0; h < H; h++)
        for (int off = 32; off > 0; off >>= 1)
            sum[h] += __shfl_xor(sum[h], off);
    float inv[H];
#pragma unroll
    for (int h = 0; h < H; h++) inv[h] = 1.0f / (sum[h] + 1e-16f);
    for (int i = beg + lane; i < end; i += 64)
#pragma unroll
        for (int h = 0; h < H; h++)
            alpha[(size_t)i * H + h] *= inv[h];
}

// ---------------- layer-1 aggregation: out[d,h*256+t] = relu(sum alpha*h1[src] + b) ----------------
__global__ __launch_bounds__(256) void k_aggr1(const int* __restrict__ indptr,
                                               const int* __restrict__ ssrc,
                                               const float* __restrict__ alpha,
                                               const float* __restrict__ h1,
                                               const float* __restrict__ b,
                                               float* __restrict__ x2) {
    int d = blockIdx.x, t = threadIdx.x;
    int beg = indptr[d], end = indptr[d + 1];
    float a0 = 0.f, a1 = 0.f, a2 = 0.f, a3 = 0.f;
    for (int i = beg; i < end; i++) {
        int s = ssrc[i];
        const float* hp = &h1[(size_t)s * D1];
        float w0 = alpha[(size_t)i * 4 + 0];
        float w1 = alpha[(size_t)i * 4 + 1];
        float w2 = alpha[(size_t)i * 4 + 2];
        float w3 = alpha[(size_t)i * 4 + 3];
        a0 += w0 * hp[t];
        a1 += w1 * hp[256 + t];
        a2 += w2 * hp[512 + t];
        a3 += w3 * hp[768 + t];
    }
    size_t o = (size_t)d * D1;
    x2[o + t]       = fmaxf(a0 + b[t], 0.f);
    x2[o + 256 + t] = fmaxf(a1 + b[256 + t], 0.f);
    x2[o + 512 + t] = fmaxf(a2 + b[512 + t], 0.f);
    x2[o + 768 + t] = fmaxf(a3 + b[768 + t], 0.f);
}

// ---------------- GEMM2: [NN x D1] @ [D1 x HIDC] ----------------
// 16 nodes per block; thread t owns col t; K staged in 128-chunks
__global__ __launch_bounds__(256) void k_gemm2(const float* __restrict__ x2,
                                               const float* __restrict__ W2,
                                               float* __restrict__ h2) {
    __shared__ float4 xs[16][32];
    int t = threadIdx.x;
    int n0 = blockIdx.x * 16;
    float acc[16] = {};
    for (int k0 = 0; k0 < D1; k0 += 128) {
        __syncthreads();
        for (int idx = t; idx < 512; idx += 256) {
            int r = idx >> 5, kk = idx & 31;
            xs[r][kk] = ((const float4*)&x2[(size_t)(n0 + r) * D1 + k0])[kk];
        }
        __syncthreads();
        for (int kk = 0; kk < 32; kk++) {
            float w0 = W2[(size_t)(k0 + kk * 4 + 0) * HIDC + t];
            float w1 = W2[(size_t)(k0 + kk * 4 + 1) * HIDC + t];
            float w2 = W2[(size_t)(k0 + kk * 4 + 2) * HIDC + t];
            float w3 = W2[(size_t)(k0 + kk * 4 + 3) * HIDC + t];
#pragma unroll
            for (int r = 0; r < 16; r++) {
                float4 xv = xs[r][kk];
                acc[r] += xv.x * w0 + xv.y * w1 + xv.z * w2 + xv.w * w3;
            }
        }
    }
#pragma unroll
    for (int r = 0; r < 16; r++)
        h2[(size_t)(n0 + r) * HIDC + t] = acc[r];
}

// ---------------- layer-2 aggregation ----------------
__global__ __launch_bounds__(256) void k_aggr2(const int* __restrict__ indptr,
                                               const int* __restrict__ ssrc,
                                               const float* __restrict__ alpha,
                                               const float* __restrict__ h2,
                                               const float* __restrict__ b,
                                               float* __restrict__ x3) {
    int d = blockIdx.x, t = threadIdx.x;
    int beg = indptr[d], end = indptr[d + 1];
    float acc = 0.f;
    for (int i = beg; i < end; i++) {
        int s = ssrc[i];
        acc += alpha[i] * h2[(size_t)s * HIDC + t];
    }
    x3[(size_t)d * HIDC + t] = fmaxf(acc + b[t], 0.f);
}

// ---------------- mean pool ----------------
__global__ __launch_bounds__(256) void k_pool(const float* __restrict__ x3,
                                              float* __restrict__ pooled) {
    int t = threadIdx.x, bb = blockIdx.x;
    float acc = 0.f;
    for (int n = bb; n < NN; n += gridDim.x)
        acc += x3[(size_t)n * HIDC + t];
    atomicAdd(&pooled[t], acc);
}

// ---------------- MLP head: 256 -> 128 (gelu exact) -> 1 ----------------
__global__ __launch_bounds__(128) void k_mlp(const float* __restrict__ pooled,
                                             const float* __restrict__ Wv1,
                                             const float* __restrict__ bv1,
                                             const float* __restrict__ Wv2,
                                             const float* __restrict__ bv2,
                                             float* __restrict__ out) {
    int j = threadIdx.x;
    float s = bv1[j];
    const float invn = 1.0f / (float)NN;
    for (int c = 0; c < HIDC; c++)
        s += (pooled[c] * invn) * Wv1[c * 128 + j];
    float g = 0.5f * s * (1.0f + erff(s * 0.70710678118654752f));
    float v = g * Wv2[j];
    __shared__ float red[128];
    red[j] = v;
    __syncthreads();
    for (int off = 64; off > 0; off >>= 1) {
        if (j < off) red[j] += red[j + off];
        __syncthreads();
    }
    if (j == 0) out[0] = red[0] + bv2[0];
}

extern "C" void kernel_launch(void* const* d_in, const int* in_sizes, int n_in,
                              void* d_out, int out_size, void* d_ws, size_t ws_size,
                              hipStream_t stream) {
    const float* x_in  = (const float*)d_in[0];
    const int*   ei    = (const int*)d_in[1];
    // d_in[2] = edge_attr: ignored (GATConv has no edge_dim)
    const float* W1    = (const float*)d_in[3];
    const float* asrc1 = (const float*)d_in[4];
    const float* adst1 = (const float*)d_in[5];
    const float* b1    = (const float*)d_in[6];
    const float* W2    = (const float*)d_in[7];
    const float* asrc2 = (const float*)d_in[8];
    const float* adst2 = (const float*)d_in[9];
    const float* b2    = (const float*)d_in[10];
    const float* Wv1   = (const float*)d_in[11];
    const float* bv1   = (const float*)d_in[12];
    const float* Wv2   = (const float*)d_in[13];
    const float* bv2   = (const float*)d_in[14];
    float* out = (float*)d_out;

    char* w = (char*)d_ws;
    auto alloc = [&](size_t bytes) { char* p = w; w += (bytes + 255) & ~(size_t)255; return p; };
    float* h1     = (float*)alloc(sizeof(float) * (size_t)NN * D1);   // 40.96 MB
    float* x2     = (float*)alloc(sizeof(float) * (size_t)NN * D1);   // 40.96 MB
    float* as1    = (float*)alloc(sizeof(float) * NN * NH);
    float* ad1    = (float*)alloc(sizeof(float) * NN * NH);
    float* as2    = (float*)alloc(sizeof(float) * NN);
    float* ad2    = (float*)alloc(sizeof(float) * NN);
    float* alpha1 = (float*)alloc(sizeof(float) * (size_t)NET * NH);  // 2.72 MB
    float* alpha2 = (float*)alloc(sizeof(float) * NET);               // 0.68 MB
    float* pooled = (float*)alloc(sizeof(float) * HIDC);
    int*   counts = (int*)alloc(sizeof(int) * NN);
    int*   indptr = (int*)alloc(sizeof(int) * (NN + 1));
    int*   cursor = (int*)alloc(sizeof(int) * NN);
    int*   ssrc   = (int*)alloc(sizeof(int) * NET);
    // h1 is dead after k_aggr1/k_att<4>; alias layer-2 buffers into it
    float* h2 = h1;
    float* x3 = h1 + (size_t)NN * HIDC;

    hipMemsetAsync(counts, 0, sizeof(int) * NN, stream);
    hipMemsetAsync(pooled, 0, sizeof(float) * HIDC, stream);

    const int EB = (NET + 255) / 256;
    k_hist<<<EB, 256, 0, stream>>>(ei, counts);
    k_scan<<<1, 1024, 0, stream>>>(counts, indptr, cursor);
    k_scatter<<<EB, 256, 0, stream>>>(ei, cursor, ssrc);

    k_gemm1<<<NN / 8, 256, 0, stream>>>(x_in, W1, h1);
    k_att<4><<<NN, 256, 0, stream>>>(h1, asrc1, adst1, as1, ad1);
    k_edge_softmax<4><<<NN, 64, 0, stream>>>(indptr, ssrc, as1, ad1, alpha1);
    k_aggr1<<<NN, 256, 0, stream>>>(indptr, ssrc, alpha1, h1, b1, x2);

    k_gemm2<<<NN / 16, 256, 0, stream>>>(x2, W2, h2);
    k_att<1><<<NN, 256, 0, stream>>>(h2, asrc2, adst2, as2, ad2);
    k_edge_softmax<1><<<NN, 64, 0, stream>>>(indptr, ssrc, as2, ad2, alpha2);
    k_aggr2<<<NN, 256, 0, stream>>>(indptr, ssrc, alpha2, h2, b2, x3);

    k_pool<<<40, 256, 0, stream>>>(x3, pooled);
    k_mlp<<<1, 128, 0, stream>>>(pooled, Wv1, bv1, Wv2, bv2, out);
}